// Round 1
// baseline (574.012 us; speedup 1.0000x reference)
//
#include <hip/hip_runtime.h>
#include <hip/hip_bf16.h>

#define N_NODES 20000
#define N_FEAT  128
#define EIG     32
#define HID     64
#define N_EDGES 640000
#define M_ROWS  (N_NODES * N_FEAT)   /* 2,560,000 */
#define K_DROP  256000               /* int(M*0.1) */
#define NBINS   16384
#define LIST_CAP 4096

#define POSS_BYTES ((size_t)M_ROWS * 4)
#define HIST_BYTES (NBINS * 4)
#define META_WORDS 16
/* meta: [0]=bin B, [1]=c_before, [2]=threshold key T, [3]=cutoff index, [7]=collect count */

__device__ __forceinline__ int bin_of(float ps) {
  int b = (int)(ps * (float)NBINS);
  if (b > NBINS - 1) b = NBINS - 1;
  if (b < 0) b = 0;
  return b;
}

__global__ __launch_bounds__(256) void poss_kernel(
    const float* __restrict__ eig, const float* __restrict__ uni,
    const float* __restrict__ W1, const float* __restrict__ b1,
    const float* __restrict__ W2, const float* __restrict__ b2,
    float* __restrict__ poss, unsigned* __restrict__ hist)
{
  int row = blockIdx.x * 256 + threadIdx.x;
  if (row >= M_ROWS) return;

  float e[EIG];
  const float4* p = (const float4*)(eig + (size_t)row * EIG);
  #pragma unroll
  for (int i = 0; i < EIG / 4; ++i) {
    float4 v = p[i];
    e[4*i+0] = v.x; e[4*i+1] = v.y; e[4*i+2] = v.z; e[4*i+3] = v.w;
  }

  // logits = relu(e @ W1 + b1) @ W2 + b2 ; W1 indices are wave-uniform -> s_load
  float l0 = b2[0], l1 = b2[1];
  #pragma unroll 4
  for (int j = 0; j < HID; ++j) {
    float h = b1[j];
    #pragma unroll
    for (int k = 0; k < EIG; ++k)
      h = fmaf(e[k], W1[k * HID + j], h);
    h = fmaxf(h, 0.0f);
    l0 = fmaf(h, W2[2*j+0], l0);
    l1 = fmaf(h, W2[2*j+1], l1);
  }

  // logits = log(softmax(logits) + 1e-8)
  float mx = fmaxf(l0, l1);
  float q0 = expf(l0 - mx), q1 = expf(l1 - mx);
  float inv = 1.0f / (q0 + q1);
  float lg0 = logf(q0 * inv + 1e-8f);
  float lg1 = logf(q1 * inv + 1e-8f);

  // gumbel noise, y = softmax((logits + g)/TEMP), TEMP=1
  const float2 u = *(const float2*)(uni + (size_t)row * 2);
  float g0 = -logf(-logf(u.x));
  float g1 = -logf(-logf(u.y));
  float z0 = lg0 + g0, z1 = lg1 + g1;
  float mz = fmaxf(z0, z1);
  float e0 = expf(z0 - mz), e1 = expf(z1 - mz);
  float y0 = e0 / (e0 + e1);

  float ps = 1.0f - y0;
  ps = fminf(fmaxf(ps, 1e-6f), 1.0f);
  poss[row] = ps;
  atomicAdd(&hist[bin_of(ps)], 1u);
}

// find bin B such that cum_excl(B) < K_DROP <= cum_incl(B); store B, cum_excl
__global__ void scan_kernel(const unsigned* __restrict__ hist, unsigned* __restrict__ meta)
{
  __shared__ unsigned psum[256];
  int t = threadIdx.x;
  unsigned s = 0;
  for (int i = 0; i < NBINS / 256; ++i) s += hist[t * (NBINS / 256) + i];
  psum[t] = s;
  __syncthreads();
  if (t == 0) {
    unsigned cum = 0;
    int c = 0;
    for (; c < 256; ++c) {
      if (cum + psum[c] >= K_DROP) break;
      cum += psum[c];
    }
    int b = c * (NBINS / 256);
    for (;; ++b) {
      unsigned h = hist[b];
      if (cum + h >= K_DROP) break;
      cum += h;
    }
    meta[0] = (unsigned)b;
    meta[1] = cum;
  }
}

__global__ __launch_bounds__(256) void collect_kernel(
    const float* __restrict__ poss, unsigned* __restrict__ meta,
    unsigned* __restrict__ list)
{
  int i = blockIdx.x * 256 + threadIdx.x;
  if (i >= M_ROWS) return;
  float ps = poss[i];
  if (bin_of(ps) == (int)meta[0]) {
    unsigned p = atomicAdd(&meta[7], 1u);
    if (p < LIST_CAP) list[p] = (unsigned)i;
  }
}

// exact rank within the boundary bin, tie-break by ascending index (matches top_k)
__global__ void rank_kernel(const float* __restrict__ poss,
                            const unsigned* __restrict__ list,
                            unsigned* __restrict__ meta)
{
  __shared__ unsigned sk[LIST_CAP];
  __shared__ unsigned si[LIST_CAP];
  unsigned n = meta[7];
  if (n > LIST_CAP) n = LIST_CAP;
  unsigned target = K_DROP - meta[1] - 1;   // 0-indexed rank inside this bin
  int t = threadIdx.x;
  for (unsigned i = t; i < n; i += 256) {
    unsigned ix = list[i];
    si[i] = ix;
    sk[i] = __float_as_uint(poss[ix]);   // poss>0 so uint order == float order
  }
  __syncthreads();
  for (unsigned el = t; el < n; el += 256) {
    unsigned k = sk[el], ix = si[el];
    unsigned r = 0;
    for (unsigned j = 0; j < n; ++j)
      r += (sk[j] < k) || (sk[j] == k && si[j] < ix);
    if (r == target) { meta[2] = k; meta[3] = ix; }
  }
}

__global__ __launch_bounds__(256) void finalize_kernel(
    const float* __restrict__ x, const float* __restrict__ poss,
    const int* __restrict__ ei, const float* __restrict__ ew,
    const unsigned* __restrict__ meta, float* __restrict__ out)
{
  unsigned i = blockIdx.x * 256 + threadIdx.x;
  if (i < M_ROWS) {
    unsigned T = meta[2], cut = meta[3];
    float ps = poss[i];
    unsigned k = __float_as_uint(ps);
    bool sel = (k < T) || (k == T && i <= cut);
    float xv = x[i];
    out[i] = sel ? xv * ps : xv;
  } else if (i < M_ROWS + 2 * N_EDGES) {
    unsigned j = i - M_ROWS;
    out[i] = (float)ei[j];
  } else if (i < M_ROWS + 2 * N_EDGES + N_EDGES) {
    unsigned j = i - (M_ROWS + 2 * N_EDGES);
    out[i] = ew[j];
  }
}

extern "C" void kernel_launch(void* const* d_in, const int* in_sizes, int n_in,
                              void* d_out, int out_size, void* d_ws, size_t ws_size,
                              hipStream_t stream)
{
  const float* x   = (const float*)d_in[0];
  const int*   ei  = (const int*)d_in[1];
  const float* ew  = (const float*)d_in[2];
  const float* eig = (const float*)d_in[3];
  const float* uni = (const float*)d_in[4];
  const float* W1  = (const float*)d_in[5];
  const float* b1  = (const float*)d_in[6];
  const float* W2  = (const float*)d_in[7];
  const float* b2  = (const float*)d_in[8];
  float* out = (float*)d_out;

  char* ws = (char*)d_ws;
  float*    poss = (float*)ws;
  unsigned* hist = (unsigned*)(ws + POSS_BYTES);
  unsigned* meta = (unsigned*)(ws + POSS_BYTES + HIST_BYTES);
  unsigned* list = (unsigned*)(ws + POSS_BYTES + HIST_BYTES + META_WORDS * 4);

  hipMemsetAsync(hist, 0, HIST_BYTES + META_WORDS * 4 + LIST_CAP * 4, stream);
  poss_kernel<<<M_ROWS / 256, 256, 0, stream>>>(eig, uni, W1, b1, W2, b2, poss, hist);
  scan_kernel<<<1, 256, 0, stream>>>(hist, meta);
  collect_kernel<<<M_ROWS / 256, 256, 0, stream>>>(poss, meta, list);
  rank_kernel<<<1, 256, 0, stream>>>(poss, list, meta);
  finalize_kernel<<<(M_ROWS + 2 * N_EDGES + N_EDGES) / 256, 256, 0, stream>>>(
      x, poss, ei, ew, meta, out);
}

// Round 2
// 571.982 us; speedup vs baseline: 1.0035x; 1.0035x over previous
//
#include <hip/hip_runtime.h>
#include <hip/hip_bf16.h>

#define N_NODES 20000
#define N_FEAT  128
#define EIG     32
#define HID     64
#define N_EDGES 640000
#define M_ROWS  (N_NODES * N_FEAT)   /* 2,560,000 */
#define K_DROP  256000               /* int(M*0.1) */
#define NBINS   16384
#define LIST_CAP 4096

#define POSS_BYTES ((size_t)M_ROWS * 4)
#define HIST_BYTES (NBINS * 4)
#define META_WORDS 16
/* meta: [0]=bin B, [1]=c_before, [2]=threshold key T, [3]=cutoff index, [7]=collect count */

__device__ __forceinline__ int bin_of(float ps) {
  int b = (int)(ps * (float)NBINS);
  if (b > NBINS - 1) b = NBINS - 1;
  if (b < 0) b = 0;
  return b;
}

__global__ __launch_bounds__(256, 1) void poss_kernel(
    const float* __restrict__ eig, const float* __restrict__ uni,
    const float* __restrict__ W1, const float* __restrict__ b1,
    const float* __restrict__ W2, const float* __restrict__ b2,
    float* __restrict__ poss, unsigned* __restrict__ hist)
{
  int row = blockIdx.x * 256 + threadIdx.x;
  if (row >= M_ROWS) return;

  float e[EIG];
  const float4* p = (const float4*)(eig + (size_t)row * EIG);
  #pragma unroll
  for (int i = 0; i < EIG / 4; ++i) {
    float4 v = p[i];
    e[4*i+0] = v.x; e[4*i+1] = v.y; e[4*i+2] = v.z; e[4*i+3] = v.w;
  }
  // Pin e[] in VGPRs: makes the values opaque so the compiler cannot
  // rematerialize the global loads inside the j-loop (R1: VGPR=24 + L1/L2
  // re-read storm; 206us vs 72us FMA floor).
  #pragma unroll
  for (int i = 0; i < EIG; ++i) asm volatile("" : "+v"(e[i]));

  // logits = relu(e @ W1 + b1) @ W2 + b2 ; W1 indices are wave-uniform -> s_load
  float l0 = b2[0], l1 = b2[1];
  #pragma unroll 4
  for (int j = 0; j < HID; ++j) {
    float h = b1[j];
    #pragma unroll
    for (int k = 0; k < EIG; ++k)
      h = fmaf(e[k], W1[k * HID + j], h);
    h = fmaxf(h, 0.0f);
    l0 = fmaf(h, W2[2*j+0], l0);
    l1 = fmaf(h, W2[2*j+1], l1);
  }

  // logits = log(softmax(logits) + 1e-8)
  float mx = fmaxf(l0, l1);
  float q0 = expf(l0 - mx), q1 = expf(l1 - mx);
  float inv = 1.0f / (q0 + q1);
  float lg0 = logf(q0 * inv + 1e-8f);
  float lg1 = logf(q1 * inv + 1e-8f);

  // gumbel noise, y = softmax((logits + g)/TEMP), TEMP=1
  const float2 u = *(const float2*)(uni + (size_t)row * 2);
  float g0 = -logf(-logf(u.x));
  float g1 = -logf(-logf(u.y));
  float z0 = lg0 + g0, z1 = lg1 + g1;
  float mz = fmaxf(z0, z1);
  float e0 = expf(z0 - mz), e1 = expf(z1 - mz);
  float y0 = e0 / (e0 + e1);

  float ps = 1.0f - y0;
  ps = fminf(fmaxf(ps, 1e-6f), 1.0f);
  poss[row] = ps;
  atomicAdd(&hist[bin_of(ps)], 1u);
}

// find bin B such that cum_excl(B) < K_DROP <= cum_incl(B); store B, cum_excl
__global__ void scan_kernel(const unsigned* __restrict__ hist, unsigned* __restrict__ meta)
{
  __shared__ unsigned psum[256];
  int t = threadIdx.x;
  unsigned s = 0;
  for (int i = 0; i < NBINS / 256; ++i) s += hist[t * (NBINS / 256) + i];
  psum[t] = s;
  __syncthreads();
  if (t == 0) {
    unsigned cum = 0;
    int c = 0;
    for (; c < 256; ++c) {
      if (cum + psum[c] >= K_DROP) break;
      cum += psum[c];
    }
    int b = c * (NBINS / 256);
    for (;; ++b) {
      unsigned h = hist[b];
      if (cum + h >= K_DROP) break;
      cum += h;
    }
    meta[0] = (unsigned)b;
    meta[1] = cum;
  }
}

__global__ __launch_bounds__(256) void collect_kernel(
    const float* __restrict__ poss, unsigned* __restrict__ meta,
    unsigned* __restrict__ list)
{
  int i = blockIdx.x * 256 + threadIdx.x;
  if (i >= M_ROWS) return;
  float ps = poss[i];
  if (bin_of(ps) == (int)meta[0]) {
    unsigned p = atomicAdd(&meta[7], 1u);
    if (p < LIST_CAP) list[p] = (unsigned)i;
  }
}

// exact rank within the boundary bin, tie-break by ascending index (matches top_k)
__global__ void rank_kernel(const float* __restrict__ poss,
                            const unsigned* __restrict__ list,
                            unsigned* __restrict__ meta)
{
  __shared__ unsigned sk[LIST_CAP];
  __shared__ unsigned si[LIST_CAP];
  unsigned n = meta[7];
  if (n > LIST_CAP) n = LIST_CAP;
  unsigned target = K_DROP - meta[1] - 1;   // 0-indexed rank inside this bin
  int t = threadIdx.x;
  for (unsigned i = t; i < n; i += 256) {
    unsigned ix = list[i];
    si[i] = ix;
    sk[i] = __float_as_uint(poss[ix]);   // poss>0 so uint order == float order
  }
  __syncthreads();
  for (unsigned el = t; el < n; el += 256) {
    unsigned k = sk[el], ix = si[el];
    unsigned r = 0;
    for (unsigned j = 0; j < n; ++j)
      r += (sk[j] < k) || (sk[j] == k && si[j] < ix);
    if (r == target) { meta[2] = k; meta[3] = ix; }
  }
}

__global__ __launch_bounds__(256) void finalize_kernel(
    const float* __restrict__ x, const float* __restrict__ poss,
    const int* __restrict__ ei, const float* __restrict__ ew,
    const unsigned* __restrict__ meta, float* __restrict__ out)
{
  unsigned i = blockIdx.x * 256 + threadIdx.x;
  if (i < M_ROWS) {
    unsigned T = meta[2], cut = meta[3];
    float ps = poss[i];
    unsigned k = __float_as_uint(ps);
    bool sel = (k < T) || (k == T && i <= cut);
    float xv = x[i];
    out[i] = sel ? xv * ps : xv;
  } else if (i < M_ROWS + 2 * N_EDGES) {
    unsigned j = i - M_ROWS;
    out[i] = (float)ei[j];
  } else if (i < M_ROWS + 2 * N_EDGES + N_EDGES) {
    unsigned j = i - (M_ROWS + 2 * N_EDGES);
    out[i] = ew[j];
  }
}

extern "C" void kernel_launch(void* const* d_in, const int* in_sizes, int n_in,
                              void* d_out, int out_size, void* d_ws, size_t ws_size,
                              hipStream_t stream)
{
  const float* x   = (const float*)d_in[0];
  const int*   ei  = (const int*)d_in[1];
  const float* ew  = (const float*)d_in[2];
  const float* eig = (const float*)d_in[3];
  const float* uni = (const float*)d_in[4];
  const float* W1  = (const float*)d_in[5];
  const float* b1  = (const float*)d_in[6];
  const float* W2  = (const float*)d_in[7];
  const float* b2  = (const float*)d_in[8];
  float* out = (float*)d_out;

  char* ws = (char*)d_ws;
  float*    poss = (float*)ws;
  unsigned* hist = (unsigned*)(ws + POSS_BYTES);
  unsigned* meta = (unsigned*)(ws + POSS_BYTES + HIST_BYTES);
  unsigned* list = (unsigned*)(ws + POSS_BYTES + HIST_BYTES + META_WORDS * 4);

  hipMemsetAsync(hist, 0, HIST_BYTES + META_WORDS * 4 + LIST_CAP * 4, stream);
  poss_kernel<<<M_ROWS / 256, 256, 0, stream>>>(eig, uni, W1, b1, W2, b2, poss, hist);
  scan_kernel<<<1, 256, 0, stream>>>(hist, meta);
  collect_kernel<<<M_ROWS / 256, 256, 0, stream>>>(poss, meta, list);
  rank_kernel<<<1, 256, 0, stream>>>(poss, list, meta);
  finalize_kernel<<<(M_ROWS + 2 * N_EDGES + N_EDGES) / 256, 256, 0, stream>>>(
      x, poss, ei, ew, meta, out);
}

// Round 3
// 545.082 us; speedup vs baseline: 1.0531x; 1.0494x over previous
//
#include <hip/hip_runtime.h>
#include <hip/hip_bf16.h>

#define N_NODES 20000
#define N_FEAT  128
#define EIG     32
#define HID     64
#define N_EDGES 640000
#define M_ROWS  (N_NODES * N_FEAT)   /* 2,560,000 */
#define K_DROP  256000               /* int(M*0.1) */
#define NBINS   16384
#define LIST_CAP 4096
#define NTILES  (M_ROWS / 16)        /* 160,000 wave-tiles of 16 rows */
#define NBLK    2560

#define POSS_BYTES ((size_t)M_ROWS * 4)
#define HIST_BYTES (NBINS * 4)
#define META_WORDS 16
/* meta: [0]=bin B, [1]=c_before, [2]=threshold key T, [3]=cutoff index, [7]=collect count */

typedef __attribute__((ext_vector_type(8))) short short8;   // 8 x bf16 (4 VGPRs)
typedef __attribute__((ext_vector_type(4))) float floatx4;  // MFMA C/D

__device__ __forceinline__ short f2bf(float f) {
  unsigned u = __float_as_uint(f);
  unsigned r = u + 0x7fffu + ((u >> 16) & 1u);   // RNE-ish
  return (short)(r >> 16);
}

__device__ __forceinline__ int bin_of(float ps) {
  int b = (int)(ps * (float)NBINS);
  if (b > NBINS - 1) b = NBINS - 1;
  if (b < 0) b = 0;
  return b;
}

// Layer1 via MFMA 16x16x32 bf16 (K == EIG), layer2 via shuffle-reduced partials.
// A layout: A[m=lane&15][k=quad*8+j]; B: B[k=quad*8+j][n=lane&15];
// C: row=quad*4+reg, col=lane&15  (guide §3, HW-verified mappings m89/m120).
__global__ __launch_bounds__(256) void poss_kernel(
    const float* __restrict__ eig, const float* __restrict__ uni,
    const float* __restrict__ W1, const float* __restrict__ b1,
    const float* __restrict__ W2, const float* __restrict__ b2,
    float* __restrict__ poss, unsigned* __restrict__ hist)
{
  const int wave = threadIdx.x >> 6;
  const int lane = threadIdx.x & 63;
  const int col  = lane & 15;
  const int quad = lane >> 4;

  // B fragments for W1 (loaded once per wave, reused over grid-stride loop).
  short8 bfrag[4];
  #pragma unroll
  for (int t = 0; t < 4; ++t)
    #pragma unroll
    for (int j = 0; j < 8; ++j)
      bfrag[t][j] = f2bf(W1[(quad * 8 + j) * HID + 16 * t + col]);

  // per-lane epilogue constants: n = 16t + col
  float b1v[4], w20[4], w21[4];
  #pragma unroll
  for (int t = 0; t < 4; ++t) {
    int n = 16 * t + col;
    b1v[t] = b1[n];
    w20[t] = W2[2 * n + 0];
    w21[t] = W2[2 * n + 1];
  }
  const float b20 = b2[0], b21 = b2[1];

  for (int tile = blockIdx.x * 4 + wave; tile < NTILES; tile += NBLK * 4) {
    const int rowbase = tile * 16;

    // A fragment: row = rowbase + col, k = quad*8 + j (row-major, contiguous 32B)
    const float4* pa = (const float4*)(eig + (size_t)(rowbase + col) * EIG + quad * 8);
    float4 v0 = pa[0], v1 = pa[1];
    short8 a;
    a[0] = f2bf(v0.x); a[1] = f2bf(v0.y); a[2] = f2bf(v0.z); a[3] = f2bf(v0.w);
    a[4] = f2bf(v1.x); a[5] = f2bf(v1.y); a[6] = f2bf(v1.z); a[7] = f2bf(v1.w);

    floatx4 c[4];
    const floatx4 z = {0.f, 0.f, 0.f, 0.f};
    #pragma unroll
    for (int t = 0; t < 4; ++t)
      c[t] = __builtin_amdgcn_mfma_f32_16x16x32_bf16(a, bfrag[t], z, 0, 0, 0);

    // layer2 partials: lane holds h[row=quad*4+r][n=16t+col] in c[t][r]
    float p0[4] = {0, 0, 0, 0}, p1[4] = {0, 0, 0, 0};
    #pragma unroll
    for (int t = 0; t < 4; ++t)
      #pragma unroll
      for (int r = 0; r < 4; ++r) {
        float h = fmaxf(c[t][r] + b1v[t], 0.0f);
        p0[r] = fmaf(h, w20[t], p0[r]);
        p1[r] = fmaf(h, w21[t], p1[r]);
      }

    // reduce over the 16 lanes of each quad-group (n-dimension)
    #pragma unroll
    for (int s = 1; s < 16; s <<= 1) {
      #pragma unroll
      for (int r = 0; r < 4; ++r) {
        p0[r] += __shfl_xor(p0[r], s, 64);
        p1[r] += __shfl_xor(p1[r], s, 64);
      }
    }

    // epilogue: 16 lanes/wave (col<4) each finish one row
    if (col < 4) {
      int r = col;
      float l0 = ((r == 0) ? p0[0] : (r == 1) ? p0[1] : (r == 2) ? p0[2] : p0[3]) + b20;
      float l1 = ((r == 0) ? p1[0] : (r == 1) ? p1[1] : (r == 2) ? p1[2] : p1[3]) + b21;
      int row = rowbase + quad * 4 + r;

      float mx = fmaxf(l0, l1);
      float q0 = expf(l0 - mx), q1 = expf(l1 - mx);
      float inv = 1.0f / (q0 + q1);
      float lg0 = logf(q0 * inv + 1e-8f);
      float lg1 = logf(q1 * inv + 1e-8f);

      const float2 u = *(const float2*)(uni + (size_t)row * 2);
      float g0 = -logf(-logf(u.x));
      float g1 = -logf(-logf(u.y));
      float z0 = lg0 + g0, z1 = lg1 + g1;
      float mz = fmaxf(z0, z1);
      float e0 = expf(z0 - mz), e1 = expf(z1 - mz);
      float y0 = e0 / (e0 + e1);

      float ps = 1.0f - y0;
      ps = fminf(fmaxf(ps, 1e-6f), 1.0f);
      poss[row] = ps;
      atomicAdd(&hist[bin_of(ps)], 1u);
    }
  }
}

// find bin B such that cum_excl(B) < K_DROP <= cum_incl(B); store B, cum_excl
__global__ void scan_kernel(const unsigned* __restrict__ hist, unsigned* __restrict__ meta)
{
  __shared__ unsigned psum[256];
  int t = threadIdx.x;
  unsigned s = 0;
  for (int i = 0; i < NBINS / 256; ++i) s += hist[t * (NBINS / 256) + i];
  psum[t] = s;
  __syncthreads();
  if (t == 0) {
    unsigned cum = 0;
    int c = 0;
    for (; c < 256; ++c) {
      if (cum + psum[c] >= K_DROP) break;
      cum += psum[c];
    }
    int b = c * (NBINS / 256);
    for (;; ++b) {
      unsigned h = hist[b];
      if (cum + h >= K_DROP) break;
      cum += h;
    }
    meta[0] = (unsigned)b;
    meta[1] = cum;
  }
}

__global__ __launch_bounds__(256) void collect_kernel(
    const float* __restrict__ poss, unsigned* __restrict__ meta,
    unsigned* __restrict__ list)
{
  int i = blockIdx.x * 256 + threadIdx.x;
  if (i >= M_ROWS) return;
  float ps = poss[i];
  if (bin_of(ps) == (int)meta[0]) {
    unsigned p = atomicAdd(&meta[7], 1u);
    if (p < LIST_CAP) list[p] = (unsigned)i;
  }
}

// exact rank within the boundary bin, tie-break by ascending index (matches top_k)
__global__ void rank_kernel(const float* __restrict__ poss,
                            const unsigned* __restrict__ list,
                            unsigned* __restrict__ meta)
{
  __shared__ unsigned sk[LIST_CAP];
  __shared__ unsigned si[LIST_CAP];
  unsigned n = meta[7];
  if (n > LIST_CAP) n = LIST_CAP;
  unsigned target = K_DROP - meta[1] - 1;   // 0-indexed rank inside this bin
  int t = threadIdx.x;
  for (unsigned i = t; i < n; i += 256) {
    unsigned ix = list[i];
    si[i] = ix;
    sk[i] = __float_as_uint(poss[ix]);   // poss>0 so uint order == float order
  }
  __syncthreads();
  for (unsigned el = t; el < n; el += 256) {
    unsigned k = sk[el], ix = si[el];
    unsigned r = 0;
    for (unsigned j = 0; j < n; ++j)
      r += (sk[j] < k) || (sk[j] == k && si[j] < ix);
    if (r == target) { meta[2] = k; meta[3] = ix; }
  }
}

__global__ __launch_bounds__(256) void finalize_kernel(
    const float* __restrict__ x, const float* __restrict__ poss,
    const int* __restrict__ ei, const float* __restrict__ ew,
    const unsigned* __restrict__ meta, float* __restrict__ out)
{
  unsigned i = blockIdx.x * 256 + threadIdx.x;
  if (i < M_ROWS) {
    unsigned T = meta[2], cut = meta[3];
    float ps = poss[i];
    unsigned k = __float_as_uint(ps);
    bool sel = (k < T) || (k == T && i <= cut);
    float xv = x[i];
    out[i] = sel ? xv * ps : xv;
  } else if (i < M_ROWS + 2 * N_EDGES) {
    unsigned j = i - M_ROWS;
    out[i] = (float)ei[j];
  } else if (i < M_ROWS + 2 * N_EDGES + N_EDGES) {
    unsigned j = i - (M_ROWS + 2 * N_EDGES);
    out[i] = ew[j];
  }
}

extern "C" void kernel_launch(void* const* d_in, const int* in_sizes, int n_in,
                              void* d_out, int out_size, void* d_ws, size_t ws_size,
                              hipStream_t stream)
{
  const float* x   = (const float*)d_in[0];
  const int*   ei  = (const int*)d_in[1];
  const float* ew  = (const float*)d_in[2];
  const float* eig = (const float*)d_in[3];
  const float* uni = (const float*)d_in[4];
  const float* W1  = (const float*)d_in[5];
  const float* b1  = (const float*)d_in[6];
  const float* W2  = (const float*)d_in[7];
  const float* b2  = (const float*)d_in[8];
  float* out = (float*)d_out;

  char* ws = (char*)d_ws;
  float*    poss = (float*)ws;
  unsigned* hist = (unsigned*)(ws + POSS_BYTES);
  unsigned* meta = (unsigned*)(ws + POSS_BYTES + HIST_BYTES);
  unsigned* list = (unsigned*)(ws + POSS_BYTES + HIST_BYTES + META_WORDS * 4);

  hipMemsetAsync(hist, 0, HIST_BYTES + META_WORDS * 4 + LIST_CAP * 4, stream);
  poss_kernel<<<NBLK, 256, 0, stream>>>(eig, uni, W1, b1, W2, b2, poss, hist);
  scan_kernel<<<1, 256, 0, stream>>>(hist, meta);
  collect_kernel<<<M_ROWS / 256, 256, 0, stream>>>(poss, meta, list);
  rank_kernel<<<1, 256, 0, stream>>>(poss, list, meta);
  finalize_kernel<<<(M_ROWS + 2 * N_EDGES + N_EDGES) / 256, 256, 0, stream>>>(
      x, poss, ei, ew, meta, out);
}

// Round 4
// 538.427 us; speedup vs baseline: 1.0661x; 1.0124x over previous
//
#include <hip/hip_runtime.h>
#include <hip/hip_bf16.h>

#define N_NODES 20000
#define N_FEAT  128
#define EIG     32
#define HID     64
#define N_EDGES 640000
#define M_ROWS  (N_NODES * N_FEAT)   /* 2,560,000 */
#define K_DROP  256000               /* int(M*0.1) */
#define NBINS   16384
#define LIST_CAP 4096
#define NTILES  (M_ROWS / 16)        /* 160,000 wave-tiles of 16 rows */
#define NBLK    2560

#define POSS_BYTES ((size_t)M_ROWS * 4)
#define HIST_BYTES (NBINS * 4)
#define META_WORDS 16
/* meta: [0]=bin B, [1]=c_before, [2]=threshold key T, [3]=cutoff index, [7]=collect count */

typedef __attribute__((ext_vector_type(8))) short short8;   // 8 x bf16 (4 VGPRs)
typedef __attribute__((ext_vector_type(4))) float floatx4;  // MFMA C/D

__device__ __forceinline__ short f2bf(float f) {
  unsigned u = __float_as_uint(f);
  unsigned r = u + 0x7fffu + ((u >> 16) & 1u);   // RNE
  return (short)(r >> 16);
}

// packed f32x2 -> bf16x2 (v_cvt_pk_bf16_f32)
__device__ __forceinline__ short2 f2bf2(float x, float y) {
  float2 f; f.x = x; f.y = y;
  __hip_bfloat162 h = __float22bfloat162_rn(f);
  union { __hip_bfloat162 h2; short2 s2; } u;
  u.h2 = h;
  return u.s2;
}

__device__ __forceinline__ int bin_of(float ps) {
  int b = (int)(ps * (float)NBINS);
  if (b > NBINS - 1) b = NBINS - 1;
  if (b < 0) b = 0;
  return b;
}

// Layer1 via MFMA 16x16x32 bf16 (K == EIG). Layer2 reduced to a single
// logit DIFFERENCE (poss depends only on l1-l0), shuffle-reduced.
// Epilogue collapsed algebraically:
//   poss = sigmoid(z1-z0) = A*Lx / (A*Lx + B*Ly),
//   t = e^(l1-l0), A = t+eps*(1+t), B = 1+eps*(1+t), Lx=-ln(ux), Ly=-ln(uy)
// (exact rewrite of softmax->log(+eps)->gumbel->softmax; log base cancels).
__global__ __launch_bounds__(256) void poss_kernel(
    const float* __restrict__ eig, const float* __restrict__ uni,
    const float* __restrict__ W1, const float* __restrict__ b1,
    const float* __restrict__ W2, const float* __restrict__ b2,
    float* __restrict__ poss, unsigned* __restrict__ hist)
{
  const int wave = threadIdx.x >> 6;
  const int lane = threadIdx.x & 63;
  const int col  = lane & 15;
  const int quad = lane >> 4;

  // B fragments for W1 (loaded once per wave, reused over grid-stride loop).
  short8 bfrag[4];
  #pragma unroll
  for (int t = 0; t < 4; ++t)
    #pragma unroll
    for (int j = 0; j < 8; ++j)
      bfrag[t][j] = f2bf(W1[(quad * 8 + j) * HID + 16 * t + col]);

  // per-lane epilogue constants: n = 16t + col ; only the W2 column DIFF matters
  float b1v[4], wd[4];
  #pragma unroll
  for (int t = 0; t < 4; ++t) {
    int n = 16 * t + col;
    b1v[t] = b1[n];
    wd[t] = W2[2 * n + 1] - W2[2 * n + 0];
  }
  const float bd = b2[1] - b2[0];

  for (int tile = blockIdx.x * 4 + wave; tile < NTILES; tile += NBLK * 4) {
    const int rowbase = tile * 16;

    // A fragment: row = rowbase + col, k = quad*8 + j (row-major, contiguous 32B)
    const float4* pa = (const float4*)(eig + (size_t)(rowbase + col) * EIG + quad * 8);
    float4 v0 = pa[0], v1 = pa[1];
    union { short8 v; short2 h[4]; } au;
    au.h[0] = f2bf2(v0.x, v0.y);
    au.h[1] = f2bf2(v0.z, v0.w);
    au.h[2] = f2bf2(v1.x, v1.y);
    au.h[3] = f2bf2(v1.z, v1.w);

    floatx4 c[4];
    const floatx4 z = {0.f, 0.f, 0.f, 0.f};
    #pragma unroll
    for (int t = 0; t < 4; ++t)
      c[t] = __builtin_amdgcn_mfma_f32_16x16x32_bf16(au.v, bfrag[t], z, 0, 0, 0);

    // layer2 diff partials: lane holds h[row=quad*4+r][n=16t+col] in c[t][r]
    float pd[4] = {0, 0, 0, 0};
    #pragma unroll
    for (int t = 0; t < 4; ++t)
      #pragma unroll
      for (int r = 0; r < 4; ++r) {
        float h = fmaxf(c[t][r] + b1v[t], 0.0f);
        pd[r] = fmaf(h, wd[t], pd[r]);
      }

    // reduce over the 16 lanes of each quad-group (n-dimension)
    #pragma unroll
    for (int s = 1; s < 16; s <<= 1)
      #pragma unroll
      for (int r = 0; r < 4; ++r)
        pd[r] += __shfl_xor(pd[r], s, 64);

    // epilogue: 16 lanes/wave (col<4) each finish one row
    if (col < 4) {
      int r = col;
      float ldiff = ((r == 0) ? pd[0] : (r == 1) ? pd[1] : (r == 2) ? pd[2] : pd[3]) + bd;
      int row = rowbase + quad * 4 + r;

      const float2 u = *(const float2*)(uni + (size_t)row * 2);
      float t = __expf(ldiff);              // e^(l1-l0)
      float e1t = 1e-8f * (1.0f + t);
      float A = t + e1t;                    // ∝ s1+eps
      float B = 1.0f + e1t;                 // ∝ s0+eps
      float Lx = -__logf(u.x);              // -ln(ux) > 0
      float Ly = -__logf(u.y);
      float num = A * Lx;
      float ps = __fdividef(num, num + B * Ly);
      ps = fminf(fmaxf(ps, 1e-6f), 1.0f);
      poss[row] = ps;
      atomicAdd(&hist[bin_of(ps)], 1u);
    }
  }
}

// find bin B such that cum_excl(B) < K_DROP <= cum_incl(B); store B, cum_excl
__global__ void scan_kernel(const unsigned* __restrict__ hist, unsigned* __restrict__ meta)
{
  __shared__ unsigned psum[256];
  int t = threadIdx.x;
  unsigned s = 0;
  for (int i = 0; i < NBINS / 256; ++i) s += hist[t * (NBINS / 256) + i];
  psum[t] = s;
  __syncthreads();
  if (t == 0) {
    unsigned cum = 0;
    int c = 0;
    for (; c < 256; ++c) {
      if (cum + psum[c] >= K_DROP) break;
      cum += psum[c];
    }
    int b = c * (NBINS / 256);
    for (;; ++b) {
      unsigned h = hist[b];
      if (cum + h >= K_DROP) break;
      cum += h;
    }
    meta[0] = (unsigned)b;
    meta[1] = cum;
  }
}

__global__ __launch_bounds__(256) void collect_kernel(
    const float* __restrict__ poss, unsigned* __restrict__ meta,
    unsigned* __restrict__ list)
{
  int i = blockIdx.x * 256 + threadIdx.x;
  if (i >= M_ROWS) return;
  float ps = poss[i];
  if (bin_of(ps) == (int)meta[0]) {
    unsigned p = atomicAdd(&meta[7], 1u);
    if (p < LIST_CAP) list[p] = (unsigned)i;
  }
}

// exact rank within the boundary bin, tie-break by ascending index (matches top_k)
__global__ void rank_kernel(const float* __restrict__ poss,
                            const unsigned* __restrict__ list,
                            unsigned* __restrict__ meta)
{
  __shared__ unsigned sk[LIST_CAP];
  __shared__ unsigned si[LIST_CAP];
  unsigned n = meta[7];
  if (n > LIST_CAP) n = LIST_CAP;
  unsigned target = K_DROP - meta[1] - 1;   // 0-indexed rank inside this bin
  int t = threadIdx.x;
  for (unsigned i = t; i < n; i += 256) {
    unsigned ix = list[i];
    si[i] = ix;
    sk[i] = __float_as_uint(poss[ix]);   // poss>0 so uint order == float order
  }
  __syncthreads();
  for (unsigned el = t; el < n; el += 256) {
    unsigned k = sk[el], ix = si[el];
    unsigned r = 0;
    for (unsigned j = 0; j < n; ++j)
      r += (sk[j] < k) || (sk[j] == k && si[j] < ix);
    if (r == target) { meta[2] = k; meta[3] = ix; }
  }
}

__global__ __launch_bounds__(256) void finalize_kernel(
    const float* __restrict__ x, const float* __restrict__ poss,
    const int* __restrict__ ei, const float* __restrict__ ew,
    const unsigned* __restrict__ meta, float* __restrict__ out)
{
  unsigned i = blockIdx.x * 256 + threadIdx.x;
  if (i < M_ROWS) {
    unsigned T = meta[2], cut = meta[3];
    float ps = poss[i];
    unsigned k = __float_as_uint(ps);
    bool sel = (k < T) || (k == T && i <= cut);
    float xv = x[i];
    out[i] = sel ? xv * ps : xv;
  } else if (i < M_ROWS + 2 * N_EDGES) {
    unsigned j = i - M_ROWS;
    out[i] = (float)ei[j];
  } else if (i < M_ROWS + 2 * N_EDGES + N_EDGES) {
    unsigned j = i - (M_ROWS + 2 * N_EDGES);
    out[i] = ew[j];
  }
}

extern "C" void kernel_launch(void* const* d_in, const int* in_sizes, int n_in,
                              void* d_out, int out_size, void* d_ws, size_t ws_size,
                              hipStream_t stream)
{
  const float* x   = (const float*)d_in[0];
  const int*   ei  = (const int*)d_in[1];
  const float* ew  = (const float*)d_in[2];
  const float* eig = (const float*)d_in[3];
  const float* uni = (const float*)d_in[4];
  const float* W1  = (const float*)d_in[5];
  const float* b1  = (const float*)d_in[6];
  const float* W2  = (const float*)d_in[7];
  const float* b2  = (const float*)d_in[8];
  float* out = (float*)d_out;

  char* ws = (char*)d_ws;
  float*    poss = (float*)ws;
  unsigned* hist = (unsigned*)(ws + POSS_BYTES);
  unsigned* meta = (unsigned*)(ws + POSS_BYTES + HIST_BYTES);
  unsigned* list = (unsigned*)(ws + POSS_BYTES + HIST_BYTES + META_WORDS * 4);

  hipMemsetAsync(hist, 0, HIST_BYTES + META_WORDS * 4 + LIST_CAP * 4, stream);
  poss_kernel<<<NBLK, 256, 0, stream>>>(eig, uni, W1, b1, W2, b2, poss, hist);
  scan_kernel<<<1, 256, 0, stream>>>(hist, meta);
  collect_kernel<<<M_ROWS / 256, 256, 0, stream>>>(poss, meta, list);
  rank_kernel<<<1, 256, 0, stream>>>(poss, list, meta);
  finalize_kernel<<<(M_ROWS + 2 * N_EDGES + N_EDGES) / 256, 256, 0, stream>>>(
      x, poss, ei, ew, meta, out);
}